// Round 13
// baseline (51.496 us; speedup 1.0000x reference)
//
#include <hip/hip_runtime.h>
#include <math.h>

#define NN 128
#define MLINKS 256
#define HID 128
#define EF 17
#define BATCH 16
#define IN_DIM 86721
#define COMB 33089
#define NBLK2 259                  // ceil(33089/128)
#define PSTRIDE (NBLK2 * 128)      // 33152 floats: per-batch partial slab [p][h]
#define XC_STRIDE 16720            // compact x region (16705 floats) padded to /16

// input-row offsets
#define OFF_SD 0
#define OFF_SLOTS 256
#define OFF_SPEC 261
#define OFF_LF 321
#define OFF_BET 4673
#define OFF_ADJ 4801

// compact-x offsets (ck = k - 16384)
#define XC_SD 0
#define XC_SLOTS 256
#define XC_CB 261
#define XC_LB 291
#define XC_AL 321

__device__ __forceinline__ float fast_tanh(float x) {
    x = fminf(fmaxf(x, -15.f), 15.f);
    const float e = __expf(2.f * x);
    return (e - 1.f) / (e + 1.f);
}

// ---------------------------------------------------------------------------
// Kernel 1: front end. 256 blocks (16 batches x 16 rowgroups) x 1024 threads.
// (R12 version, unchanged.)
// ---------------------------------------------------------------------------
__global__ __launch_bounds__(1024) void k_front(const float* __restrict__ in,
                                                const float* __restrict__ WH,
                                                const float* __restrict__ WE,
                                                const float* __restrict__ a_attn,
                                                float* __restrict__ xc,
                                                float* __restrict__ sabec) {
    const int bid = blockIdx.x;
    const int b = bid >> 4;
    const int rg = bid & 15;
    const int tid = threadIdx.x;
    const int wv = tid >> 6, lane = tid & 63;
    const float* row = in + (size_t)b * IN_DIM;

    // issue-early: this wave's softmax row (consumed at the end)
    float adj1 = 0.f, adj2 = 0.f;
    const int irow = rg * 8 + wv;
    if (wv < 8) {
        adj1 = row[OFF_ADJ + irow * NN + lane];
        adj2 = row[OFF_ADJ + irow * NN + 64 + lane];
    }

    __shared__ float lf_lds[MLINKS * EF];   // 17 KB
    __shared__ float lfm[EF];
    __shared__ float WH_s[HID];
    __shared__ float bet_s[NN];
    __shared__ float red0[HID], red1[HID], red2[HID];
    __shared__ float scb[4];                // d1, d2, se, ec0
    __shared__ float betsum_s;

    for (int i = tid; i < MLINKS * EF; i += 1024) lf_lds[i] = row[OFF_LF + i];
    if (tid < 128) bet_s[tid] = row[OFF_BET + tid];
    else if (tid < 256) WH_s[tid - 128] = WH[tid - 128];
    __syncthreads();

    if (tid < EF * 32) {
        const int e = tid >> 5, c = tid & 31;
        float s = 0.f;
        #pragma unroll
        for (int m = c; m < MLINKS; m += 32) s += lf_lds[m * EF + e];
        #pragma unroll
        for (int d = 1; d < 32; d <<= 1) s += __shfl_xor(s, d);
        if (c == 0) lfm[e] = s * (1.0f / 256.0f);
    }
    if (tid >= 960) {       // betsum on wave 15
        const int l2 = tid - 960;
        float v = bet_s[l2] + bet_s[l2 + 64];
        #pragma unroll
        for (int d = 1; d < 64; d <<= 1) v += __shfl_xor(v, d);
        if (l2 == 0) betsum_s = v;
    }
    __syncthreads();

    if (tid < HID) {
        float ecv = 0.f;
        #pragma unroll
        for (int e = 0; e < EF; ++e) ecv += lfm[e] * WE[e * HID + tid];
        red0[tid] = WH_s[tid] * a_attn[tid];
        red1[tid] = WH_s[tid] * a_attn[HID + tid];
        red2[tid] = ecv * a_attn[2 * HID + tid];
        if (tid == 0) scb[3] = ecv;         // ec0
    }
    __syncthreads();
    if (wv < 3) {
        const float* ra = (wv == 0) ? red0 : (wv == 1) ? red1 : red2;
        float v = ra[lane] + ra[lane + 64];
        #pragma unroll
        for (int d = 1; d < 64; d <<= 1) v += __shfl_xor(v, d);
        if (lane == 0) scb[wv] = v;
    }
    __syncthreads();

    const float d1 = scb[0], d2 = scb[1], se = scb[2], ec0 = scb[3];
    const float bsum = betsum_s;
    float* xr = xc + (size_t)b * XC_STRIDE;

    if (wv < 8) {
        const int i = irow;
        const float betA = bet_s[lane], betB = bet_s[lane + 64];
        const float sq = bet_s[i] * d1 + se;
        float e1 = (adj1 > 0.f) ? __expf(fast_tanh(sq + betA * d2)) : 0.f;
        float e2 = (adj2 > 0.f) ? __expf(fast_tanh(sq + betB * d2)) : 0.f;
        float s  = e1 + e2;
        float sb = e1 * betA + e2 * betB;
        #pragma unroll
        for (int d = 1; d < 64; d <<= 1) {
            s  += __shfl_xor(s, d);
            sb += __shfl_xor(sb, d);
        }
        float inv;
        if (s > 0.f) {
            inv = 1.0f / s;
        } else {            // all-masked row: jax softmax -> uniform 1/128
            e1 = 1.f; e2 = 1.f; sb = bsum; inv = 1.0f / 128.0f;
        }
        xr[XC_AL + i * NN + lane]      = e1 * inv;
        xr[XC_AL + i * NN + 64 + lane] = e2 * inv;
        if (lane == 0) sabec[b * NN + i] = ec0 * sb * inv;
    }

    if (rg == 0) {
        if (tid < 256) {
            xr[XC_SD + tid] = row[OFF_SD + tid];
        } else if (tid < 261) {
            xr[XC_SLOTS + (tid - 256)] = row[OFF_SLOTS + (tid - 256)];
        } else if (tid < 291) {
            const int idx = tid - 261, k = idx / 6, c = idx % 6;
            xr[XC_CB + idx] = row[OFF_SPEC + k * 12 + c];
        } else if (tid < 321) {
            const int idx = tid - 291, k = idx / 6, c = idx % 6;
            xr[XC_LB + idx] = row[OFF_SPEC + k * 12 + 6 + c];
        }
    }
}

// ---------------------------------------------------------------------------
// Kernel 2: split-K GEMM over W0 (R12 version, unchanged).
// ---------------------------------------------------------------------------
__global__ __launch_bounds__(1024) void k_gemm0(const float* __restrict__ xcin,
                                                const float* __restrict__ sabec,
                                                const float* __restrict__ WH,
                                                const float* __restrict__ W0,
                                                const float* __restrict__ Wr,
                                                float* __restrict__ part) {
    const int p = blockIdx.x;
    const int tid = threadIdx.x;
    const int kq  = tid >> 8;        // 0..3: k quarter
    const int sub = tid & 255;
    const int g = sub >> 5;          // 0..7 -> batches 2g, 2g+1
    const int c = sub & 31;          // float4 column group

    __shared__ float xs[BATCH][128];
    __shared__ float WH_s[HID];
    __shared__ float sab16[BATCH];
    __shared__ float4 redA[3][256];
    __shared__ float4 redB[3][256];

    const float4* __restrict__ W0v =
        reinterpret_cast<const float4*>(W0 + (size_t)p * 128 * HID);

    // issue-early: warm the first W0 rows of this k-quarter
    if (p != NBLK2 - 1) {
        #pragma unroll
        for (int t = 0; t < 4; ++t) {
            const float4 wp = W0v[(kq * 32 + t * 8) * 32 + c];
            asm volatile("" :: "v"(wp.x), "v"(wp.y), "v"(wp.z), "v"(wp.w));
        }
    }

    if (p < 128) {
        if (tid < HID)   WH_s[tid]  = WH[tid];
        else if (tid >= 128 && tid < 144) sab16[tid - 128] = sabec[(tid - 128) * NN + p];
        __syncthreads();
        for (int idx = tid; idx < BATCH * 128; idx += 1024) {
            const int bb = idx >> 7, kk = idx & 127;
            xs[bb][kk] = sab16[bb] * WH_s[kk];
        }
    } else {
        const int k0 = p * 128;
        const int c0 = k0 - 16384;
        const int klen = (COMB - k0 < 128) ? (COMB - k0) : 128;
        for (int idx = tid; idx < BATCH * 128; idx += 1024) {
            const int bb = idx >> 7, kk = idx & 127;
            xs[bb][kk] = (kk < klen) ? xcin[(size_t)bb * XC_STRIDE + c0 + kk] : 0.f;
        }
    }

    // prefetch Wr (256 KB) into L2/L3 so k_tail isn't HBM-cold
    {
        const int pidx = p * 1024 + tid;
        if (pidx < 16384) {
            const float4 wp = reinterpret_cast<const float4*>(Wr)[pidx];
            asm volatile("" :: "v"(wp.x), "v"(wp.y), "v"(wp.z), "v"(wp.w));
        }
    }
    __syncthreads();

    float4 acc0 = {0.f, 0.f, 0.f, 0.f};
    float4 acc1 = {0.f, 0.f, 0.f, 0.f};

    if (p != NBLK2 - 1) {
        #pragma unroll 16
        for (int j = 0; j < 32; ++j) {
            const int kk = kq * 32 + j;
            const float4 w = W0v[kk * 32 + c];
            const float xa = xs[2 * g][kk];
            const float xb = xs[2 * g + 1][kk];
            acc0.x += xa * w.x; acc0.y += xa * w.y; acc0.z += xa * w.z; acc0.w += xa * w.w;
            acc1.x += xb * w.x; acc1.y += xb * w.y; acc1.z += xb * w.z; acc1.w += xb * w.w;
        }
    } else {
        const int klen = COMB - (NBLK2 - 1) * 128;   // 65
        const int kend = (kq * 32 + 32 < klen) ? kq * 32 + 32 : klen;
        for (int kk = kq * 32; kk < kend; ++kk) {
            const float4 w = W0v[kk * 32 + c];
            const float xa = xs[2 * g][kk];
            const float xb = xs[2 * g + 1][kk];
            acc0.x += xa * w.x; acc0.y += xa * w.y; acc0.z += xa * w.z; acc0.w += xa * w.w;
            acc1.x += xb * w.x; acc1.y += xb * w.y; acc1.z += xb * w.z; acc1.w += xb * w.w;
        }
    }

    if (kq > 0) { redA[kq - 1][sub] = acc0; redB[kq - 1][sub] = acc1; }
    __syncthreads();
    if (kq == 0) {
        #pragma unroll
        for (int t = 0; t < 3; ++t) {
            const float4 oA = redA[t][sub], oB = redB[t][sub];
            acc0.x += oA.x; acc0.y += oA.y; acc0.z += oA.z; acc0.w += oA.w;
            acc1.x += oB.x; acc1.y += oB.y; acc1.z += oB.z; acc1.w += oB.w;
        }
        float4* pA = reinterpret_cast<float4*>(part + (size_t)(2 * g) * PSTRIDE + p * 128);
        float4* pB = reinterpret_cast<float4*>(part + (size_t)(2 * g + 1) * PSTRIDE + p * 128);
        pA[c] = acc0;
        pB[c] = acc1;
    }
}

// ---------------------------------------------------------------------------
// Kernel 3: fused partial-reduce + 4-layer ReLU MLP (R12 version, unchanged).
// ---------------------------------------------------------------------------
__global__ __launch_bounds__(1024) void k_tail(const float* __restrict__ part,
                                               const float* __restrict__ b0,
                                               const float* __restrict__ Wr,
                                               const float* __restrict__ br,
                                               float* __restrict__ out) {
    const int b = blockIdx.x;
    const int tid = threadIdx.x;
    const int h = tid & 127;
    const int q = tid >> 7;            // 0..7

    __shared__ float xs[2][HID];
    __shared__ float red[8][HID];

    float wpre[4][16];
    float brpre[4];
    #pragma unroll
    for (int L = 0; L < 4; ++L) {
        brpre[L] = br[L * HID + h];
        #pragma unroll
        for (int j = 0; j < 16; ++j)
            wpre[L][j] = Wr[(size_t)L * HID * HID + (q * 16 + j) * HID + h];
    }

    {
        const float* pb = part + (size_t)b * PSTRIDE + h;
        float s = 0.f;
        #pragma unroll 16
        for (int j = 0; j < 32; ++j)
            s += pb[(size_t)(q * 32 + j) * 128];
        if (q < 3) s += pb[(size_t)(256 + q) * 128];
        red[q][h] = s;
    }
    __syncthreads();
    if (q == 0) {
        float t = ((red[0][h] + red[1][h]) + (red[2][h] + red[3][h]))
                + ((red[4][h] + red[5][h]) + (red[6][h] + red[7][h])) + b0[h];
        xs[0][h] = fmaxf(t, 0.f);
    }
    __syncthreads();

    int cur = 0;
    #pragma unroll
    for (int L = 0; L < 4; ++L) {
        float acc = 0.f;
        #pragma unroll
        for (int j = 0; j < 16; ++j)
            acc += xs[cur][q * 16 + j] * wpre[L][j];
        red[q][h] = acc;
        __syncthreads();
        if (q == 0) {
            float t = ((red[0][h] + red[1][h]) + (red[2][h] + red[3][h]))
                    + ((red[4][h] + red[5][h]) + (red[6][h] + red[7][h]))
                    + brpre[L];
            xs[cur ^ 1][h] = fmaxf(t, 0.f);
        }
        cur ^= 1;
        __syncthreads();
    }
    if (tid < HID) out[b * HID + tid] = xs[cur][tid];
}

// ---------------------------------------------------------------------------
// ATTRIBUTION EXPERIMENT: every kernel launched TWICE (idempotent pure
// functions -> identical output, bit-deterministic). Measures the marginal
// cost of a full second pipeline: fixed_overhead = 2*dur(R12) - dur(this).
// ---------------------------------------------------------------------------
extern "C" void kernel_launch(void* const* d_in, const int* in_sizes, int n_in,
                              void* d_out, int out_size, void* d_ws, size_t ws_size,
                              hipStream_t stream) {
    const float* in     = (const float*)d_in[0];
    const float* WH     = (const float*)d_in[1];
    const float* WE     = (const float*)d_in[2];
    const float* a_attn = (const float*)d_in[3];
    const float* W0     = (const float*)d_in[4];
    const float* b0     = (const float*)d_in[5];
    const float* Wr     = (const float*)d_in[6];
    const float* br     = (const float*)d_in[7];
    float* out = (float*)d_out;

    float* ws    = (float*)d_ws;
    float* xc    = ws;                                    // 16 * 16720
    float* part  = xc + (size_t)BATCH * XC_STRIDE;        // 16 * 33152
    float* sabec = part + (size_t)BATCH * PSTRIDE;        // 2048

    hipLaunchKernelGGL(k_front, dim3(256), dim3(1024), 0, stream,
                       in, WH, WE, a_attn, xc, sabec);
    hipLaunchKernelGGL(k_front, dim3(256), dim3(1024), 0, stream,
                       in, WH, WE, a_attn, xc, sabec);
    hipLaunchKernelGGL(k_gemm0, dim3(NBLK2), dim3(1024), 0, stream,
                       xc, sabec, WH, W0, Wr, part);
    hipLaunchKernelGGL(k_gemm0, dim3(NBLK2), dim3(1024), 0, stream,
                       xc, sabec, WH, W0, Wr, part);
    hipLaunchKernelGGL(k_tail, dim3(BATCH), dim3(1024), 0, stream,
                       part, b0, Wr, br, out);
    hipLaunchKernelGGL(k_tail, dim3(BATCH), dim3(1024), 0, stream,
                       part, b0, Wr, br, out);
}

// Round 14
// 28.885 us; speedup vs baseline: 1.7828x; 1.7828x over previous
//
#include <hip/hip_runtime.h>
#include <math.h>

#define NN 128
#define MLINKS 256
#define HID 128
#define EF 17
#define BATCH 16
#define IN_DIM 86721
#define COMB 33089
#define NBLK2 259                  // ceil(33089/128)
#define PSTRIDE (NBLK2 * 128)      // 33152 floats: per-batch partial slab [p][h]
#define XC_STRIDE 16720            // compact x region (16705 floats) padded to /16

// input-row offsets
#define OFF_SD 0
#define OFF_SLOTS 256
#define OFF_SPEC 261
#define OFF_LF 321
#define OFF_BET 4673
#define OFF_ADJ 4801

// compact-x offsets (ck = k - 16384)
#define XC_SD 0
#define XC_SLOTS 256
#define XC_CB 261
#define XC_LB 291
#define XC_AL 321

__device__ __forceinline__ float fast_tanh(float x) {
    x = fminf(fmaxf(x, -15.f), 15.f);
    const float e = __expf(2.f * x);
    return (e - 1.f) / (e + 1.f);
}

// ---------------------------------------------------------------------------
// Kernel 1: front end. 256 blocks (16 batches x 16 rowgroups) x 1024 threads.
// (R12 version, unchanged.)
// ---------------------------------------------------------------------------
__global__ __launch_bounds__(1024) void k_front(const float* __restrict__ in,
                                                const float* __restrict__ WH,
                                                const float* __restrict__ WE,
                                                const float* __restrict__ a_attn,
                                                float* __restrict__ xc,
                                                float* __restrict__ sabec) {
    const int bid = blockIdx.x;
    const int b = bid >> 4;
    const int rg = bid & 15;
    const int tid = threadIdx.x;
    const int wv = tid >> 6, lane = tid & 63;
    const float* row = in + (size_t)b * IN_DIM;

    // issue-early: this wave's softmax row (consumed at the end)
    float adj1 = 0.f, adj2 = 0.f;
    const int irow = rg * 8 + wv;
    if (wv < 8) {
        adj1 = row[OFF_ADJ + irow * NN + lane];
        adj2 = row[OFF_ADJ + irow * NN + 64 + lane];
    }

    __shared__ float lf_lds[MLINKS * EF];   // 17 KB
    __shared__ float lfm[EF];
    __shared__ float WH_s[HID];
    __shared__ float bet_s[NN];
    __shared__ float red0[HID], red1[HID], red2[HID];
    __shared__ float scb[4];                // d1, d2, se, ec0
    __shared__ float betsum_s;

    for (int i = tid; i < MLINKS * EF; i += 1024) lf_lds[i] = row[OFF_LF + i];
    if (tid < 128) bet_s[tid] = row[OFF_BET + tid];
    else if (tid < 256) WH_s[tid - 128] = WH[tid - 128];
    __syncthreads();

    if (tid < EF * 32) {
        const int e = tid >> 5, c = tid & 31;
        float s = 0.f;
        #pragma unroll
        for (int m = c; m < MLINKS; m += 32) s += lf_lds[m * EF + e];
        #pragma unroll
        for (int d = 1; d < 32; d <<= 1) s += __shfl_xor(s, d);
        if (c == 0) lfm[e] = s * (1.0f / 256.0f);
    }
    if (tid >= 960) {       // betsum on wave 15
        const int l2 = tid - 960;
        float v = bet_s[l2] + bet_s[l2 + 64];
        #pragma unroll
        for (int d = 1; d < 64; d <<= 1) v += __shfl_xor(v, d);
        if (l2 == 0) betsum_s = v;
    }
    __syncthreads();

    if (tid < HID) {
        float ecv = 0.f;
        #pragma unroll
        for (int e = 0; e < EF; ++e) ecv += lfm[e] * WE[e * HID + tid];
        red0[tid] = WH_s[tid] * a_attn[tid];
        red1[tid] = WH_s[tid] * a_attn[HID + tid];
        red2[tid] = ecv * a_attn[2 * HID + tid];
        if (tid == 0) scb[3] = ecv;         // ec0
    }
    __syncthreads();
    if (wv < 3) {
        const float* ra = (wv == 0) ? red0 : (wv == 1) ? red1 : red2;
        float v = ra[lane] + ra[lane + 64];
        #pragma unroll
        for (int d = 1; d < 64; d <<= 1) v += __shfl_xor(v, d);
        if (lane == 0) scb[wv] = v;
    }
    __syncthreads();

    const float d1 = scb[0], d2 = scb[1], se = scb[2], ec0 = scb[3];
    const float bsum = betsum_s;
    float* xr = xc + (size_t)b * XC_STRIDE;

    if (wv < 8) {
        const int i = irow;
        const float betA = bet_s[lane], betB = bet_s[lane + 64];
        const float sq = bet_s[i] * d1 + se;
        float e1 = (adj1 > 0.f) ? __expf(fast_tanh(sq + betA * d2)) : 0.f;
        float e2 = (adj2 > 0.f) ? __expf(fast_tanh(sq + betB * d2)) : 0.f;
        float s  = e1 + e2;
        float sb = e1 * betA + e2 * betB;
        #pragma unroll
        for (int d = 1; d < 64; d <<= 1) {
            s  += __shfl_xor(s, d);
            sb += __shfl_xor(sb, d);
        }
        float inv;
        if (s > 0.f) {
            inv = 1.0f / s;
        } else {            // all-masked row: jax softmax -> uniform 1/128
            e1 = 1.f; e2 = 1.f; sb = bsum; inv = 1.0f / 128.0f;
        }
        xr[XC_AL + i * NN + lane]      = e1 * inv;
        xr[XC_AL + i * NN + 64 + lane] = e2 * inv;
        if (lane == 0) sabec[b * NN + i] = ec0 * sb * inv;
    }

    if (rg == 0) {
        if (tid < 256) {
            xr[XC_SD + tid] = row[OFF_SD + tid];
        } else if (tid < 261) {
            xr[XC_SLOTS + (tid - 256)] = row[OFF_SLOTS + (tid - 256)];
        } else if (tid < 291) {
            const int idx = tid - 261, k = idx / 6, c = idx % 6;
            xr[XC_CB + idx] = row[OFF_SPEC + k * 12 + c];
        } else if (tid < 321) {
            const int idx = tid - 291, k = idx / 6, c = idx % 6;
            xr[XC_LB + idx] = row[OFF_SPEC + k * 12 + 6 + c];
        }
    }
}

// ---------------------------------------------------------------------------
// Kernel 2: split-K GEMM over W0. 259 blocks x 1024 threads, k split 4 ways,
// LDS combine. WASTE REMOVED vs R12: no 259x-replicated Wr prefetch (66 MB
// of L2/L3 traffic), no W0 warm-up double-read (4 MB) — k_tail register-
// prefetches Wr itself, hidden under its partial reduce.
// ---------------------------------------------------------------------------
__global__ __launch_bounds__(1024) void k_gemm0(const float* __restrict__ xcin,
                                                const float* __restrict__ sabec,
                                                const float* __restrict__ WH,
                                                const float* __restrict__ W0,
                                                float* __restrict__ part) {
    const int p = blockIdx.x;
    const int tid = threadIdx.x;
    const int kq  = tid >> 8;        // 0..3: k quarter
    const int sub = tid & 255;
    const int g = sub >> 5;          // 0..7 -> batches 2g, 2g+1
    const int c = sub & 31;          // float4 column group

    __shared__ float xs[BATCH][128];
    __shared__ float WH_s[HID];
    __shared__ float sab16[BATCH];
    __shared__ float4 redA[3][256];
    __shared__ float4 redB[3][256];

    const float4* __restrict__ W0v =
        reinterpret_cast<const float4*>(W0 + (size_t)p * 128 * HID);

    if (p < 128) {
        if (tid < HID)   WH_s[tid]  = WH[tid];
        else if (tid >= 128 && tid < 144) sab16[tid - 128] = sabec[(tid - 128) * NN + p];
        __syncthreads();
        for (int idx = tid; idx < BATCH * 128; idx += 1024) {
            const int bb = idx >> 7, kk = idx & 127;
            xs[bb][kk] = sab16[bb] * WH_s[kk];
        }
    } else {
        const int k0 = p * 128;
        const int c0 = k0 - 16384;
        const int klen = (COMB - k0 < 128) ? (COMB - k0) : 128;
        for (int idx = tid; idx < BATCH * 128; idx += 1024) {
            const int bb = idx >> 7, kk = idx & 127;
            xs[bb][kk] = (kk < klen) ? xcin[(size_t)bb * XC_STRIDE + c0 + kk] : 0.f;
        }
    }
    __syncthreads();

    // ---- split-K GEMM: part[:, p, :] = xs @ W0[p*128 : p*128+128, :]
    float4 acc0 = {0.f, 0.f, 0.f, 0.f};
    float4 acc1 = {0.f, 0.f, 0.f, 0.f};

    if (p != NBLK2 - 1) {
        #pragma unroll 16
        for (int j = 0; j < 32; ++j) {
            const int kk = kq * 32 + j;
            const float4 w = W0v[kk * 32 + c];
            const float xa = xs[2 * g][kk];
            const float xb = xs[2 * g + 1][kk];
            acc0.x += xa * w.x; acc0.y += xa * w.y; acc0.z += xa * w.z; acc0.w += xa * w.w;
            acc1.x += xb * w.x; acc1.y += xb * w.y; acc1.z += xb * w.z; acc1.w += xb * w.w;
        }
    } else {
        const int klen = COMB - (NBLK2 - 1) * 128;   // 65
        const int kend = (kq * 32 + 32 < klen) ? kq * 32 + 32 : klen;
        for (int kk = kq * 32; kk < kend; ++kk) {
            const float4 w = W0v[kk * 32 + c];
            const float xa = xs[2 * g][kk];
            const float xb = xs[2 * g + 1][kk];
            acc0.x += xa * w.x; acc0.y += xa * w.y; acc0.z += xa * w.z; acc0.w += xa * w.w;
            acc1.x += xb * w.x; acc1.y += xb * w.y; acc1.z += xb * w.z; acc1.w += xb * w.w;
        }
    }

    if (kq > 0) { redA[kq - 1][sub] = acc0; redB[kq - 1][sub] = acc1; }
    __syncthreads();
    if (kq == 0) {
        #pragma unroll
        for (int t = 0; t < 3; ++t) {
            const float4 oA = redA[t][sub], oB = redB[t][sub];
            acc0.x += oA.x; acc0.y += oA.y; acc0.z += oA.z; acc0.w += oA.w;
            acc1.x += oB.x; acc1.y += oB.y; acc1.z += oB.z; acc1.w += oB.w;
        }
        float4* pA = reinterpret_cast<float4*>(part + (size_t)(2 * g) * PSTRIDE + p * 128);
        float4* pB = reinterpret_cast<float4*>(part + (size_t)(2 * g + 1) * PSTRIDE + p * 128);
        pA[c] = acc0;
        pB[c] = acc1;
    }
}

// ---------------------------------------------------------------------------
// Kernel 3: fused partial-reduce + 4-layer ReLU MLP (R12 version, unchanged):
// all 4 layers' W slices register-prefetched before the reduce.
// ---------------------------------------------------------------------------
__global__ __launch_bounds__(1024) void k_tail(const float* __restrict__ part,
                                               const float* __restrict__ b0,
                                               const float* __restrict__ Wr,
                                               const float* __restrict__ br,
                                               float* __restrict__ out) {
    const int b = blockIdx.x;
    const int tid = threadIdx.x;
    const int h = tid & 127;
    const int q = tid >> 7;            // 0..7

    __shared__ float xs[2][HID];
    __shared__ float red[8][HID];

    float wpre[4][16];
    float brpre[4];
    #pragma unroll
    for (int L = 0; L < 4; ++L) {
        brpre[L] = br[L * HID + h];
        #pragma unroll
        for (int j = 0; j < 16; ++j)
            wpre[L][j] = Wr[(size_t)L * HID * HID + (q * 16 + j) * HID + h];
    }

    {
        const float* pb = part + (size_t)b * PSTRIDE + h;
        float s = 0.f;
        #pragma unroll 16
        for (int j = 0; j < 32; ++j)
            s += pb[(size_t)(q * 32 + j) * 128];
        if (q < 3) s += pb[(size_t)(256 + q) * 128];
        red[q][h] = s;
    }
    __syncthreads();
    if (q == 0) {
        float t = ((red[0][h] + red[1][h]) + (red[2][h] + red[3][h]))
                + ((red[4][h] + red[5][h]) + (red[6][h] + red[7][h])) + b0[h];
        xs[0][h] = fmaxf(t, 0.f);
    }
    __syncthreads();

    int cur = 0;
    #pragma unroll
    for (int L = 0; L < 4; ++L) {
        float acc = 0.f;
        #pragma unroll
        for (int j = 0; j < 16; ++j)
            acc += xs[cur][q * 16 + j] * wpre[L][j];
        red[q][h] = acc;
        __syncthreads();
        if (q == 0) {
            float t = ((red[0][h] + red[1][h]) + (red[2][h] + red[3][h]))
                    + ((red[4][h] + red[5][h]) + (red[6][h] + red[7][h]))
                    + brpre[L];
            xs[cur ^ 1][h] = fmaxf(t, 0.f);
        }
        cur ^= 1;
        __syncthreads();
    }
    if (tid < HID) out[b * HID + tid] = xs[cur][tid];
}

// ---------------------------------------------------------------------------
extern "C" void kernel_launch(void* const* d_in, const int* in_sizes, int n_in,
                              void* d_out, int out_size, void* d_ws, size_t ws_size,
                              hipStream_t stream) {
    const float* in     = (const float*)d_in[0];
    const float* WH     = (const float*)d_in[1];
    const float* WE     = (const float*)d_in[2];
    const float* a_attn = (const float*)d_in[3];
    const float* W0     = (const float*)d_in[4];
    const float* b0     = (const float*)d_in[5];
    const float* Wr     = (const float*)d_in[6];
    const float* br     = (const float*)d_in[7];
    float* out = (float*)d_out;

    float* ws    = (float*)d_ws;
    float* xc    = ws;                                    // 16 * 16720
    float* part  = xc + (size_t)BATCH * XC_STRIDE;        // 16 * 33152
    float* sabec = part + (size_t)BATCH * PSTRIDE;        // 2048

    hipLaunchKernelGGL(k_front, dim3(256), dim3(1024), 0, stream,
                       in, WH, WE, a_attn, xc, sabec);
    hipLaunchKernelGGL(k_gemm0, dim3(NBLK2), dim3(1024), 0, stream,
                       xc, sabec, WH, W0, part);
    hipLaunchKernelGGL(k_tail, dim3(BATCH), dim3(1024), 0, stream,
                       part, b0, Wr, br, out);
}